// Round 1
// baseline (2670.993 us; speedup 1.0000x reference)
//
#include <hip/hip_runtime.h>
#include <cstdint>

#define HID 256
static constexpr int    NNODES = 100000;
static constexpr int    NEDGES = 300000;
static constexpr size_t NH     = (size_t)NNODES * HID;  // 25,600,000 floats

// ---------------------------------------------------------------- zero
__global__ void zero_f32_k(float4* __restrict__ p, size_t n4) {
    size_t i      = (size_t)blockIdx.x * blockDim.x + threadIdx.x;
    size_t stride = (size_t)gridDim.x * blockDim.x;
    float4 z = make_float4(0.f, 0.f, 0.f, 0.f);
    for (; i < n4; i += stride) p[i] = z;
}

// ---------------------------------------------------------------- degrees
__global__ void count_deg_k(const int* __restrict__ src, const int* __restrict__ dst,
                            float* __restrict__ degout, float* __restrict__ degin) {
    int e = blockIdx.x * blockDim.x + threadIdx.x;
    if (e < NEDGES) {
        atomicAdd(degout + src[e], 1.0f);
        atomicAdd(degin  + dst[e], 1.0f);
    }
}

__global__ void finalize_norm_k(float* __restrict__ degout, float* __restrict__ degin,
                                const float* __restrict__ sw, float* __restrict__ tail) {
    int i = blockIdx.x * blockDim.x + threadIdx.x;
    if (i < NNODES) {
        degout[i] = rsqrtf(fmaxf(degout[i], 1.0f));
        degin[i]  = rsqrtf(fmaxf(degin[i], 1.0f));
    }
    if (i < 5) tail[i] = sw[i];   // semantic_weight passthrough
}

// ---------------------------------------------------------------- GEMM
// C[m][n] = sum_k A[m][k] * B'[k][n]  (+bias, row scale, relu per template)
// BT=1: B is [256][K] row-major, B'[k][n] = B[n][k]   (proj: x @ W.T)
// BT=0: B is [K][256] row-major, B'[k][n] = B[k][n]   (final: agg @ W)
// RS=0: none; RS=1: out=(acc+bias)*rowscale[m]; RS=2: out=acc*rowscale[m]+bias
template <int BT, int RELU, int RS>
__global__ __launch_bounds__(256) void gemm64_k(
    const float* __restrict__ A, const float* __restrict__ B,
    const float* __restrict__ bias, const float* __restrict__ rowscale,
    float* __restrict__ C, int M, int K)
{
    __shared__ float As[16][68];
    __shared__ float Bs[16][68];
    const int tid = threadIdx.x;
    const int tx  = tid & 15;        // output col group
    const int ty  = tid >> 4;        // output row group
    const int m0  = blockIdx.x * 64;
    const int n0  = blockIdx.y * 64;

    const int lrow = tid >> 2;       // 0..63
    const int lkc  = (tid & 3) * 4;  // 0,4,8,12
    const int bk   = tid >> 4;       // 0..15  (NN layout)
    const int bnc  = (tid & 15) * 4; // 0..60  (NN layout)

    float acc[4][4];
#pragma unroll
    for (int i = 0; i < 4; ++i)
#pragma unroll
        for (int j = 0; j < 4; ++j) acc[i][j] = 0.f;

    for (int k0 = 0; k0 < K; k0 += 16) {
        // A tile: [64 rows][16 k]
        {
            int gm = m0 + lrow;
            float4 v = make_float4(0.f, 0.f, 0.f, 0.f);
            if (gm < M) v = *(const float4*)(A + (size_t)gm * K + k0 + lkc);
            As[lkc + 0][lrow] = v.x; As[lkc + 1][lrow] = v.y;
            As[lkc + 2][lrow] = v.z; As[lkc + 3][lrow] = v.w;
        }
        if (BT) {
            // W[n][k], n in [n0, n0+64): always in-bounds (N=256)
            float4 v = *(const float4*)(B + (size_t)(n0 + lrow) * K + k0 + lkc);
            Bs[lkc + 0][lrow] = v.x; Bs[lkc + 1][lrow] = v.y;
            Bs[lkc + 2][lrow] = v.z; Bs[lkc + 3][lrow] = v.w;
        } else {
            // W[k][n]
            float4 v = *(const float4*)(B + (size_t)(k0 + bk) * HID + n0 + bnc);
            *(float4*)&Bs[bk][bnc] = v;
        }
        __syncthreads();
#pragma unroll
        for (int kk = 0; kk < 16; ++kk) {
            float4 a = *(const float4*)&As[kk][ty * 4];
            float4 b = *(const float4*)&Bs[kk][tx * 4];
            float af[4] = {a.x, a.y, a.z, a.w};
            float bf[4] = {b.x, b.y, b.z, b.w};
#pragma unroll
            for (int i = 0; i < 4; ++i)
#pragma unroll
                for (int j = 0; j < 4; ++j)
                    acc[i][j] = fmaf(af[i], bf[j], acc[i][j]);
        }
        __syncthreads();
    }

    float4 bb = *(const float4*)(bias + n0 + tx * 4);
    float bf[4] = {bb.x, bb.y, bb.z, bb.w};
#pragma unroll
    for (int i = 0; i < 4; ++i) {
        int gm = m0 + ty * 4 + i;
        if (gm < M) {
            float rs = (RS != 0) ? rowscale[gm] : 1.0f;
            float o[4];
#pragma unroll
            for (int j = 0; j < 4; ++j) {
                if (RS == 1)      o[j] = (acc[i][j] + bf[j]) * rs;
                else if (RS == 2) o[j] = fmaf(acc[i][j], rs, bf[j]);
                else              o[j] = acc[i][j] + bf[j];
                if (RELU) o[j] = fmaxf(o[j], 0.f);
            }
            float4 ov = make_float4(o[0], o[1], o[2], o[3]);
            *(float4*)(C + (size_t)gm * HID + n0 + tx * 4) = ov;
        }
    }
}

// ---------------------------------------------------------------- scatter-add
// agg[dst[e]] += h[src[e]]   (norm_out already folded into h)
__global__ __launch_bounds__(256) void scatter_agg_k(
    const float* __restrict__ h, const int* __restrict__ src,
    const int* __restrict__ dst, float* __restrict__ agg)
{
    int e = blockIdx.x * 4 + (threadIdx.x >> 6);
    if (e >= NEDGES) return;
    int lane = threadIdx.x & 63;
    int s = src[e], d = dst[e];
    float4 v = ((const float4*)(h + (size_t)s * HID))[lane];
    float* a = agg + (size_t)d * HID + lane * 4;
    atomicAdd(a + 0, v.x);
    atomicAdd(a + 1, v.y);
    atomicAdd(a + 2, v.z);
    atomicAdd(a + 3, v.w);
}

// ---------------------------------------------------------------- layer-1 epilogue
// h1 = relu(agg * norm_in + gc1_bias) * norm_out   (norm_out folded for layer 2)
__global__ void l1_epilogue_k(float* __restrict__ h, const float* __restrict__ nin,
                              const float* __restrict__ nout, const float* __restrict__ bias)
{
    size_t idx = (size_t)blockIdx.x * blockDim.x + threadIdx.x;
    if (idx >= NH / 4) return;
    int node = (int)(idx >> 6);
    int c4   = (int)(idx & 63);
    float4 v  = ((float4*)h)[idx];
    float  a  = nin[node];
    float  b  = nout[node];
    float4 bb = ((const float4*)bias)[c4];
    v.x = fmaxf(fmaf(v.x, a, bb.x), 0.f) * b;
    v.y = fmaxf(fmaf(v.y, a, bb.y), 0.f) * b;
    v.z = fmaxf(fmaf(v.z, a, bb.z), 0.f) * b;
    v.w = fmaxf(fmaf(v.w, a, bb.w), 0.f) * b;
    ((float4*)h)[idx] = v;
}

// ---------------------------------------------------------------- launch
extern "C" void kernel_launch(void* const* d_in, const int* in_sizes, int n_in,
                              void* d_out, int out_size, void* d_ws, size_t ws_size,
                              hipStream_t stream)
{
    const float* feat0    = (const float*)d_in[0];
    const float* feat1    = (const float*)d_in[1];
    const float* feat2    = (const float*)d_in[2];
    const float* fc_w0    = (const float*)d_in[3];
    const float* fc_b0    = (const float*)d_in[4];
    const float* fc_w1    = (const float*)d_in[5];
    const float* fc_b1    = (const float*)d_in[6];
    const float* fc_w2    = (const float*)d_in[7];
    const float* fc_b2    = (const float*)d_in[8];
    const float* gc1_bias = (const float*)d_in[9];
    const float* gc2_w    = (const float*)d_in[10];
    const float* gc2_bias = (const float*)d_in[11];
    const float* sw       = (const float*)d_in[12];
    const int*   src      = (const int*)d_in[13];
    const int*   dst      = (const int*)d_in[14];

    float* ws   = (float*)d_ws;
    float* h0   = ws;                    // [NNODES][HID], proj output * norm_out
    float* h1   = ws + NH;               // layer-1 agg, then layer-1 output * norm_out
    float* agg2 = ws + 2 * NH;           // layer-2 agg
    float* nout = ws + 3 * NH;           // deg_out -> norm_out
    float* nin  = ws + 3 * NH + NNODES;  // deg_in  -> norm_in
    float* out  = (float*)d_out;

    // zero h1, agg2, deg arrays (contiguous region)
    size_t zn4 = (2 * NH + 2 * (size_t)NNODES) / 4;
    zero_f32_k<<<2048, 256, 0, stream>>>((float4*)h1, zn4);

    count_deg_k<<<(NEDGES + 255) / 256, 256, 0, stream>>>(src, dst, nout, nin);
    finalize_norm_k<<<(NNODES + 255) / 256, 256, 0, stream>>>(nout, nin, sw, out + NH);

    // projections: h0 = (feat @ W.T + b) * norm_out   [RS=1]
    dim3 g0((40000 + 63) / 64, 4);
    dim3 g1((30000 + 63) / 64, 4);
    dim3 gf((100000 + 63) / 64, 4);
    gemm64_k<1, 0, 1><<<g0, 256, 0, stream>>>(feat0, fc_w0, fc_b0, nout,
                                              h0, 40000, 512);
    gemm64_k<1, 0, 1><<<g1, 256, 0, stream>>>(feat1, fc_w1, fc_b1, nout + 40000,
                                              h0 + (size_t)40000 * HID, 30000, 256);
    gemm64_k<1, 0, 1><<<g1, 256, 0, stream>>>(feat2, fc_w2, fc_b2, nout + 70000,
                                              h0 + (size_t)70000 * HID, 30000, 128);

    // layer 1: aggregate + epilogue
    scatter_agg_k<<<(NEDGES + 3) / 4, 256, 0, stream>>>(h0, src, dst, h1);
    l1_epilogue_k<<<(int)((NH / 4 + 255) / 256), 256, 0, stream>>>(h1, nin, nout, gc1_bias);

    // layer 2: aggregate + GEMM (norm_in, bias, relu fused) -> d_out
    scatter_agg_k<<<(NEDGES + 3) / 4, 256, 0, stream>>>(h1, src, dst, agg2);
    gemm64_k<0, 1, 2><<<gf, 256, 0, stream>>>(agg2, gc2_w, gc2_bias, nin,
                                              out, 100000, 256);
}

// Round 3
// 757.138 us; speedup vs baseline: 3.5277x; 3.5277x over previous
//
#include <hip/hip_runtime.h>
#include <cstdint>

#define HID 256
static constexpr int    NNODES = 100000;
static constexpr int    NEDGES = 300000;
static constexpr size_t NH     = (size_t)NNODES * HID;  // 25,600,000 floats
static constexpr int    SCAN_B = 256;
static constexpr int    NSBLK  = (NNODES + SCAN_B - 1) / SCAN_B;  // 391

// ---------------------------------------------------------------- zero ints
__global__ void zero_i32_k(int* __restrict__ p, int n) {
    int i = blockIdx.x * blockDim.x + threadIdx.x;
    if (i < n) p[i] = 0;
}

// ---------------------------------------------------------------- degrees
__global__ void count_deg_k(const int* __restrict__ src, const int* __restrict__ dst,
                            int* __restrict__ degout, int* __restrict__ degin) {
    int e = blockIdx.x * blockDim.x + threadIdx.x;
    if (e < NEDGES) {
        atomicAdd(degout + src[e], 1);
        atomicAdd(degin  + dst[e], 1);
    }
}

__global__ void finalize_norm_k(const int* __restrict__ degout, const int* __restrict__ degin,
                                float* __restrict__ nout, float* __restrict__ nin,
                                const float* __restrict__ sw, float* __restrict__ tail) {
    int i = blockIdx.x * blockDim.x + threadIdx.x;
    if (i < NNODES) {
        nout[i] = rsqrtf(fmaxf((float)degout[i], 1.0f));
        nin[i]  = rsqrtf(fmaxf((float)degin[i], 1.0f));
    }
    if (i < 5) tail[i] = sw[i];   // semantic_weight passthrough
}

// ---------------------------------------------------------------- scan (exclusive, 3-pass)
__global__ void scan_a_k(const int* __restrict__ degin, int* __restrict__ row_off,
                         int* __restrict__ bsums) {
    __shared__ int sm[SCAN_B];
    int t = threadIdx.x;
    int g = blockIdx.x * SCAN_B + t;
    int v = (g < NNODES) ? degin[g] : 0;
    sm[t] = v;
    __syncthreads();
#pragma unroll
    for (int off = 1; off < SCAN_B; off <<= 1) {
        int x = (t >= off) ? sm[t - off] : 0;
        __syncthreads();
        sm[t] += x;
        __syncthreads();
    }
    if (g < NNODES) row_off[g] = sm[t] - v;   // exclusive within block
    if (t == SCAN_B - 1) bsums[blockIdx.x] = sm[t];
}

__global__ void scan_b_k(int* __restrict__ bsums) {
    __shared__ int sm[512];
    int t = threadIdx.x;
    int v = (t < NSBLK) ? bsums[t] : 0;
    sm[t] = v;
    __syncthreads();
#pragma unroll
    for (int off = 1; off < 512; off <<= 1) {
        int x = (t >= off) ? sm[t - off] : 0;
        __syncthreads();
        sm[t] += x;
        __syncthreads();
    }
    if (t < NSBLK) bsums[t] = sm[t] - v;      // exclusive
}

__global__ void scan_c_k(int* __restrict__ row_off, const int* __restrict__ bsums) {
    int g = blockIdx.x * SCAN_B + threadIdx.x;
    if (g < NNODES) row_off[g] += bsums[blockIdx.x];
    if (g == 0) row_off[NNODES] = NEDGES;
}

// ---------------------------------------------------------------- CSR fill
__global__ void fill_csr_k(const int* __restrict__ src, const int* __restrict__ dst,
                           const int* __restrict__ row_off, int* __restrict__ cursor,
                           int* __restrict__ csr_src) {
    int e = blockIdx.x * blockDim.x + threadIdx.x;
    if (e < NEDGES) {
        int d = dst[e];
        int pos = row_off[d] + atomicAdd(cursor + d, 1);
        csr_src[pos] = src[e];
    }
}

// ---------------------------------------------------------------- gather-aggregate
// out[node] = sum_{e in in-edges(node)} h[csr_src[e]]   (norm_out pre-folded into h)
// EPI=1: out = relu(acc*nin + bias) * nout  (layer-1 epilogue + fold for layer 2)
template <int EPI>
__global__ __launch_bounds__(256) void gather_agg_k(
    const float* __restrict__ h, const int* __restrict__ row_off,
    const int* __restrict__ csr_src, const float* __restrict__ nin,
    const float* __restrict__ nout, const float* __restrict__ bias,
    float* __restrict__ out)
{
    int node = blockIdx.x * 4 + (threadIdx.x >> 6);
    if (node >= NNODES) return;
    int lane = threadIdx.x & 63;
    int beg = row_off[node], end = row_off[node + 1];
    float4 acc = make_float4(0.f, 0.f, 0.f, 0.f);
    for (int e = beg; e < end; ++e) {
        int s = csr_src[e];
        float4 v = ((const float4*)(h + (size_t)s * HID))[lane];
        acc.x += v.x; acc.y += v.y; acc.z += v.z; acc.w += v.w;
    }
    if (EPI) {
        float a = nin[node], b = nout[node];
        float4 bb = ((const float4*)bias)[lane];
        acc.x = fmaxf(fmaf(acc.x, a, bb.x), 0.f) * b;
        acc.y = fmaxf(fmaf(acc.y, a, bb.y), 0.f) * b;
        acc.z = fmaxf(fmaf(acc.z, a, bb.z), 0.f) * b;
        acc.w = fmaxf(fmaf(acc.w, a, bb.w), 0.f) * b;
    }
    ((float4*)(out + (size_t)node * HID))[lane] = acc;
}

// ---------------------------------------------------------------- GEMM
// C[m][n] = sum_k A[m][k] * B'[k][n]  (+bias, row scale, relu per template)
// BT=1: B is [256][K] row-major, B'[k][n] = B[n][k]   (proj: x @ W.T)
// BT=0: B is [K][256] row-major, B'[k][n] = B[k][n]   (final: agg @ W)
// RS=0: none; RS=1: out=(acc+bias)*rowscale[m]; RS=2: out=acc*rowscale[m]+bias
template <int BT, int RELU, int RS>
__global__ __launch_bounds__(256) void gemm64_k(
    const float* __restrict__ A, const float* __restrict__ B,
    const float* __restrict__ bias, const float* __restrict__ rowscale,
    float* __restrict__ C, int M, int K)
{
    __shared__ float As[16][68];
    __shared__ float Bs[16][68];
    const int tid = threadIdx.x;
    const int tx  = tid & 15;        // output col group
    const int ty  = tid >> 4;        // output row group
    const int m0  = blockIdx.x * 64;
    const int n0  = blockIdx.y * 64;

    const int lrow = tid >> 2;       // 0..63
    const int lkc  = (tid & 3) * 4;  // 0,4,8,12
    const int bk   = tid >> 4;       // 0..15  (NN layout)
    const int bnc  = (tid & 15) * 4; // 0..60  (NN layout)

    float acc[4][4];
#pragma unroll
    for (int i = 0; i < 4; ++i)
#pragma unroll
        for (int j = 0; j < 4; ++j) acc[i][j] = 0.f;

    for (int k0 = 0; k0 < K; k0 += 16) {
        {
            int gm = m0 + lrow;
            float4 v = make_float4(0.f, 0.f, 0.f, 0.f);
            if (gm < M) v = *(const float4*)(A + (size_t)gm * K + k0 + lkc);
            As[lkc + 0][lrow] = v.x; As[lkc + 1][lrow] = v.y;
            As[lkc + 2][lrow] = v.z; As[lkc + 3][lrow] = v.w;
        }
        if (BT) {
            float4 v = *(const float4*)(B + (size_t)(n0 + lrow) * K + k0 + lkc);
            Bs[lkc + 0][lrow] = v.x; Bs[lkc + 1][lrow] = v.y;
            Bs[lkc + 2][lrow] = v.z; Bs[lkc + 3][lrow] = v.w;
        } else {
            float4 v = *(const float4*)(B + (size_t)(k0 + bk) * HID + n0 + bnc);
            *(float4*)&Bs[bk][bnc] = v;
        }
        __syncthreads();
#pragma unroll
        for (int kk = 0; kk < 16; ++kk) {
            float4 a = *(const float4*)&As[kk][ty * 4];
            float4 b = *(const float4*)&Bs[kk][tx * 4];
            float af[4] = {a.x, a.y, a.z, a.w};
            float bf[4] = {b.x, b.y, b.z, b.w};
#pragma unroll
            for (int i = 0; i < 4; ++i)
#pragma unroll
                for (int j = 0; j < 4; ++j)
                    acc[i][j] = fmaf(af[i], bf[j], acc[i][j]);
        }
        __syncthreads();
    }

    float4 bb = *(const float4*)(bias + n0 + tx * 4);
    float bf[4] = {bb.x, bb.y, bb.z, bb.w};
#pragma unroll
    for (int i = 0; i < 4; ++i) {
        int gm = m0 + ty * 4 + i;
        if (gm < M) {
            float rs = (RS != 0) ? rowscale[gm] : 1.0f;
            float o[4];
#pragma unroll
            for (int j = 0; j < 4; ++j) {
                if (RS == 1)      o[j] = (acc[i][j] + bf[j]) * rs;
                else if (RS == 2) o[j] = fmaf(acc[i][j], rs, bf[j]);
                else              o[j] = acc[i][j] + bf[j];
                if (RELU) o[j] = fmaxf(o[j], 0.f);
            }
            float4 ov = make_float4(o[0], o[1], o[2], o[3]);
            *(float4*)(C + (size_t)gm * HID + n0 + tx * 4) = ov;
        }
    }
}

// ---------------------------------------------------------------- launch
extern "C" void kernel_launch(void* const* d_in, const int* in_sizes, int n_in,
                              void* d_out, int out_size, void* d_ws, size_t ws_size,
                              hipStream_t stream)
{
    const float* feat0    = (const float*)d_in[0];
    const float* feat1    = (const float*)d_in[1];
    const float* feat2    = (const float*)d_in[2];
    const float* fc_w0    = (const float*)d_in[3];
    const float* fc_b0    = (const float*)d_in[4];
    const float* fc_w1    = (const float*)d_in[5];
    const float* fc_b1    = (const float*)d_in[6];
    const float* fc_w2    = (const float*)d_in[7];
    const float* fc_b2    = (const float*)d_in[8];
    const float* gc1_bias = (const float*)d_in[9];
    const float* gc2_w    = (const float*)d_in[10];
    const float* gc2_bias = (const float*)d_in[11];
    const float* sw       = (const float*)d_in[12];
    const int*   src      = (const int*)d_in[13];
    const int*   dst      = (const int*)d_in[14];

    float* ws   = (float*)d_ws;
    float* h0   = ws;           // [NNODES][HID]; later reused as agg2
    float* h1   = ws + NH;      // layer-1 output (* norm_out)
    float* nout = ws + 2 * NH;
    float* nin  = nout + NNODES;
    int*   ints = (int*)(nin + NNODES);
    int* deg_out = ints;                    // deg_out/deg_in/cursor zeroed together
    int* deg_in  = deg_out + NNODES;
    int* cursor  = deg_in + NNODES;
    int* row_off = cursor + NNODES;         // NNODES+1
    int* bsums   = row_off + NNODES + 1;    // 512
    int* csr_src = bsums + 512;             // NEDGES
    float* agg2  = h0;                      // alias: h0 dead after layer-1 gather
    float* out   = (float*)d_out;

    // ---- graph preprocessing
    zero_i32_k<<<(3 * NNODES + 255) / 256, 256, 0, stream>>>(deg_out, 3 * NNODES);
    count_deg_k<<<(NEDGES + 255) / 256, 256, 0, stream>>>(src, dst, deg_out, deg_in);
    finalize_norm_k<<<(NNODES + 255) / 256, 256, 0, stream>>>(deg_out, deg_in, nout, nin,
                                                              sw, out + NH);
    scan_a_k<<<NSBLK, SCAN_B, 0, stream>>>(deg_in, row_off, bsums);
    scan_b_k<<<1, 512, 0, stream>>>(bsums);
    scan_c_k<<<NSBLK, SCAN_B, 0, stream>>>(row_off, bsums);
    fill_csr_k<<<(NEDGES + 255) / 256, 256, 0, stream>>>(src, dst, row_off, cursor, csr_src);

    // ---- projections: h0 = (feat @ W.T + b) * norm_out   [RS=1]
    dim3 g0((40000 + 63) / 64, 4);
    dim3 g1((30000 + 63) / 64, 4);
    dim3 gf((100000 + 63) / 64, 4);
    gemm64_k<1, 0, 1><<<g0, 256, 0, stream>>>(feat0, fc_w0, fc_b0, nout,
                                              h0, 40000, 512);
    gemm64_k<1, 0, 1><<<g1, 256, 0, stream>>>(feat1, fc_w1, fc_b1, nout + 40000,
                                              h0 + (size_t)40000 * HID, 30000, 256);
    gemm64_k<1, 0, 1><<<g1, 256, 0, stream>>>(feat2, fc_w2, fc_b2, nout + 70000,
                                              h0 + (size_t)70000 * HID, 30000, 128);

    // ---- layer 1: gather + fused epilogue -> h1
    gather_agg_k<1><<<(NNODES + 3) / 4, 256, 0, stream>>>(h0, row_off, csr_src,
                                                          nin, nout, gc1_bias, h1);
    // ---- layer 2: gather -> agg2, then GEMM (norm_in, bias, relu fused) -> d_out
    gather_agg_k<0><<<(NNODES + 3) / 4, 256, 0, stream>>>(h1, row_off, csr_src,
                                                          nin, nout, nullptr, agg2);
    gemm64_k<0, 1, 2><<<gf, 256, 0, stream>>>(agg2, gc2_w, gc2_bias, nin,
                                              out, 100000, 256);
}

// Round 4
// 464.864 us; speedup vs baseline: 5.7458x; 1.6287x over previous
//
#include <hip/hip_runtime.h>
#include <cstdint>

#define HID 256
static constexpr int    NNODES = 100000;
static constexpr int    NEDGES = 300000;
static constexpr size_t NH     = (size_t)NNODES * HID;  // 25,600,000 elems
static constexpr int    SCAN_B = 256;
static constexpr int    NSBLK  = (NNODES + SCAN_B - 1) / SCAN_B;  // 391

typedef __attribute__((ext_vector_type(8))) short bf16x8;
typedef __attribute__((ext_vector_type(4))) float f32x4;

__device__ __forceinline__ unsigned short f2bf(float x) {   // RNE f32 -> bf16
    unsigned int u = __float_as_uint(x);
    u += 0x7fffu + ((u >> 16) & 1u);
    return (unsigned short)(u >> 16);
}
__device__ __forceinline__ float bflo(unsigned int u) { return __uint_as_float(u << 16); }
__device__ __forceinline__ float bfhi(unsigned int u) { return __uint_as_float(u & 0xffff0000u); }

// ---------------------------------------------------------------- zero ints
__global__ void zero_i32_k(int* __restrict__ p, int n) {
    int i = blockIdx.x * blockDim.x + threadIdx.x;
    if (i < n) p[i] = 0;
}

// ---------------------------------------------------------------- fp32 -> bf16 flat convert
__global__ void cvt_bf16_k(const float* __restrict__ in, unsigned short* __restrict__ o, int n4) {
    int i = blockIdx.x * blockDim.x + threadIdx.x;   // group of 4 elems
    if (i < n4) {
        float4 v = ((const float4*)in)[i];
        ushort4 w;
        w.x = f2bf(v.x); w.y = f2bf(v.y); w.z = f2bf(v.z); w.w = f2bf(v.w);
        ((ushort4*)o)[i] = w;
    }
}

// gc2_weight [K=256][N=256] fp32 -> n-major bf16 [256][256]
__global__ void cvt_w2T_k(const float* __restrict__ w, unsigned short* __restrict__ o) {
    int n = blockIdx.x, k = threadIdx.x;
    o[n * 256 + k] = f2bf(w[k * 256 + n]);
}

// ---------------------------------------------------------------- degrees
__global__ void count_deg_k(const int* __restrict__ src, const int* __restrict__ dst,
                            int* __restrict__ degout, int* __restrict__ degin) {
    int e = blockIdx.x * blockDim.x + threadIdx.x;
    if (e < NEDGES) {
        atomicAdd(degout + src[e], 1);
        atomicAdd(degin  + dst[e], 1);
    }
}

__global__ void finalize_norm_k(const int* __restrict__ degout, const int* __restrict__ degin,
                                float* __restrict__ nout, float* __restrict__ nin,
                                const float* __restrict__ sw, float* __restrict__ tail) {
    int i = blockIdx.x * blockDim.x + threadIdx.x;
    if (i < NNODES) {
        nout[i] = rsqrtf(fmaxf((float)degout[i], 1.0f));
        nin[i]  = rsqrtf(fmaxf((float)degin[i], 1.0f));
    }
    if (i < 5) tail[i] = sw[i];   // semantic_weight passthrough
}

// ---------------------------------------------------------------- scan (exclusive, 3-pass)
__global__ void scan_a_k(const int* __restrict__ degin, int* __restrict__ row_off,
                         int* __restrict__ bsums) {
    __shared__ int sm[SCAN_B];
    int t = threadIdx.x;
    int g = blockIdx.x * SCAN_B + t;
    int v = (g < NNODES) ? degin[g] : 0;
    sm[t] = v;
    __syncthreads();
#pragma unroll
    for (int off = 1; off < SCAN_B; off <<= 1) {
        int x = (t >= off) ? sm[t - off] : 0;
        __syncthreads();
        sm[t] += x;
        __syncthreads();
    }
    if (g < NNODES) row_off[g] = sm[t] - v;
    if (t == SCAN_B - 1) bsums[blockIdx.x] = sm[t];
}

__global__ void scan_b_k(int* __restrict__ bsums) {
    __shared__ int sm[512];
    int t = threadIdx.x;
    int v = (t < NSBLK) ? bsums[t] : 0;
    sm[t] = v;
    __syncthreads();
#pragma unroll
    for (int off = 1; off < 512; off <<= 1) {
        int x = (t >= off) ? sm[t - off] : 0;
        __syncthreads();
        sm[t] += x;
        __syncthreads();
    }
    if (t < NSBLK) bsums[t] = sm[t] - v;
}

__global__ void scan_c_k(int* __restrict__ row_off, const int* __restrict__ bsums) {
    int g = blockIdx.x * SCAN_B + threadIdx.x;
    if (g < NNODES) row_off[g] += bsums[blockIdx.x];
    if (g == 0) row_off[NNODES] = NEDGES;
}

// ---------------------------------------------------------------- CSR fill
__global__ void fill_csr_k(const int* __restrict__ src, const int* __restrict__ dst,
                           const int* __restrict__ row_off, int* __restrict__ cursor,
                           int* __restrict__ csr_src) {
    int e = blockIdx.x * blockDim.x + threadIdx.x;
    if (e < NEDGES) {
        int d = dst[e];
        int pos = row_off[d] + atomicAdd(cursor + d, 1);
        csr_src[pos] = src[e];
    }
}

// ---------------------------------------------------------------- gather-aggregate (bf16 h)
// out[node] = sum_{in-edges} h[csr_src[e]]   (norm_out pre-folded into h)
// EPI=1: out = relu(acc*nin + bias) * nout   (layer-1 epilogue + fold for layer 2)
template <int EPI>
__global__ __launch_bounds__(256) void gather_bf16_k(
    const unsigned short* __restrict__ h, const int* __restrict__ row_off,
    const int* __restrict__ csr_src, const float* __restrict__ nin,
    const float* __restrict__ nout, const float* __restrict__ bias,
    unsigned short* __restrict__ out)
{
    int node = blockIdx.x * 4 + (threadIdx.x >> 6);
    if (node >= NNODES) return;
    int lane = threadIdx.x & 63;
    int beg = row_off[node], end = row_off[node + 1];
    float a0 = 0.f, a1 = 0.f, a2 = 0.f, a3 = 0.f;
    for (int e = beg; e < end; ++e) {
        int s = csr_src[e];
        uint2 v = *(const uint2*)(h + (size_t)s * HID + lane * 4);
        a0 += bflo(v.x); a1 += bfhi(v.x);
        a2 += bflo(v.y); a3 += bfhi(v.y);
    }
    if (EPI) {
        float ni = nin[node], no = nout[node];
        float4 bb = *(const float4*)(bias + lane * 4);
        a0 = fmaxf(fmaf(a0, ni, bb.x), 0.f) * no;
        a1 = fmaxf(fmaf(a1, ni, bb.y), 0.f) * no;
        a2 = fmaxf(fmaf(a2, ni, bb.z), 0.f) * no;
        a3 = fmaxf(fmaf(a3, ni, bb.w), 0.f) * no;
    }
    ushort4 o;
    o.x = f2bf(a0); o.y = f2bf(a1); o.z = f2bf(a2); o.w = f2bf(a3);
    *(ushort4*)(out + (size_t)node * HID + lane * 4) = o;
}

// ---------------------------------------------------------------- MFMA GEMM
// C[M][256] = A[M][K](bf16) @ Bn'[K][256], Bn stored n-major bf16 [256][K].
// EPI=0 (proj):  C bf16, val = (acc + bias[n]) * rs[m]          (rs = norm_out)
// EPI=1 (final): C fp32, val = relu(acc * rs[m] + bias[n])      (rs = norm_in)
// Tile 128x128, BK=32, 4 waves, wave = 64x64 = 4x4 frags of 16x16x32.
// LDS chunk swizzle: 16B chunk c of row r stored at slot (c ^ ((r>>1)&3)) ->
// uniform 2-way bank aliasing (free) for both ds_write_b128 and ds_read_b128.
template <int EPI>
__global__ __launch_bounds__(256) void mfma_gemm_k(
    const unsigned short* __restrict__ A, const unsigned short* __restrict__ Bn,
    const float* __restrict__ bias, const float* __restrict__ rs,
    void* __restrict__ Cv, int M, int K)
{
    __shared__ unsigned short As[128 * 32];
    __shared__ unsigned short Bs[128 * 32];
    const int tid  = threadIdx.x;
    const int wave = tid >> 6;
    const int lane = tid & 63;
    const int wm   = wave >> 1;        // 0..1
    const int wn   = wave & 1;         // 0..1
    const int m0   = blockIdx.x * 128;
    const int n0   = blockIdx.y * 128;

    f32x4 acc[4][4];
#pragma unroll
    for (int i = 0; i < 4; ++i)
#pragma unroll
        for (int j = 0; j < 4; ++j)
#pragma unroll
            for (int r = 0; r < 4; ++r) acc[i][j][r] = 0.f;

    const int half = lane >> 4;        // k-chunk 0..3 for fragment reads
    const int l15  = lane & 15;

    for (int k0 = 0; k0 < K; k0 += 32) {
        // ---- stage A tile (128 rows x 4 chunks) ----
#pragma unroll
        for (int t = 0; t < 2; ++t) {
            int q   = tid + t * 256;          // chunk id 0..511
            int row = q >> 2, c = q & 3;
            int slot = (c ^ ((row >> 1) & 3));
            int gm  = m0 + row; if (gm > M - 1) gm = M - 1;
            uint4 v = *(const uint4*)(A + (size_t)gm * K + k0 + c * 8);
            *(uint4*)&As[(row * 4 + slot) * 8] = v;
        }
        // ---- stage B tile (128 n-rows x 4 chunks) ----
#pragma unroll
        for (int t = 0; t < 2; ++t) {
            int q   = tid + t * 256;
            int row = q >> 2, c = q & 3;
            int slot = (c ^ ((row >> 1) & 3));
            uint4 v = *(const uint4*)(Bn + (size_t)(n0 + row) * K + k0 + c * 8);
            *(uint4*)&Bs[(row * 4 + slot) * 8] = v;
        }
        __syncthreads();

        bf16x8 af[4], bfr[4];
#pragma unroll
        for (int i = 0; i < 4; ++i) {
            int m = wm * 64 + i * 16 + l15;
            int ca = half ^ ((m >> 1) & 3);
            af[i] = *(const bf16x8*)&As[(m * 4 + ca) * 8];
            int n = wn * 64 + i * 16 + l15;
            int cb = half ^ ((n >> 1) & 3);
            bfr[i] = *(const bf16x8*)&Bs[(n * 4 + cb) * 8];
        }
#pragma unroll
        for (int i = 0; i < 4; ++i)
#pragma unroll
            for (int j = 0; j < 4; ++j)
                acc[i][j] = __builtin_amdgcn_mfma_f32_16x16x32_bf16(
                    af[i], bfr[j], acc[i][j], 0, 0, 0);
        __syncthreads();
    }

    // ---- epilogue: C/D layout col=lane&15, row=(lane>>4)*4+reg ----
    float bj[4];
#pragma unroll
    for (int j = 0; j < 4; ++j) bj[j] = bias[n0 + wn * 64 + j * 16 + l15];

#pragma unroll
    for (int i = 0; i < 4; ++i)
#pragma unroll
        for (int r = 0; r < 4; ++r) {
            int m = m0 + wm * 64 + i * 16 + (lane >> 4) * 4 + r;
            if (m >= M) continue;
            float rsm = rs[m];
#pragma unroll
            for (int j = 0; j < 4; ++j) {
                int n = n0 + wn * 64 + j * 16 + l15;
                float v = acc[i][j][r];
                if (EPI == 0) {
                    v = (v + bj[j]) * rsm;
                    ((unsigned short*)Cv)[(size_t)m * HID + n] = f2bf(v);
                } else {
                    v = fmaxf(fmaf(v, rsm, bj[j]), 0.f);
                    ((float*)Cv)[(size_t)m * HID + n] = v;
                }
            }
        }
}

// ---------------------------------------------------------------- launch
extern "C" void kernel_launch(void* const* d_in, const int* in_sizes, int n_in,
                              void* d_out, int out_size, void* d_ws, size_t ws_size,
                              hipStream_t stream)
{
    const float* feat0    = (const float*)d_in[0];
    const float* feat1    = (const float*)d_in[1];
    const float* feat2    = (const float*)d_in[2];
    const float* fc_w0    = (const float*)d_in[3];
    const float* fc_b0    = (const float*)d_in[4];
    const float* fc_w1    = (const float*)d_in[5];
    const float* fc_b1    = (const float*)d_in[6];
    const float* fc_w2    = (const float*)d_in[7];
    const float* fc_b2    = (const float*)d_in[8];
    const float* gc1_bias = (const float*)d_in[9];
    const float* gc2_w    = (const float*)d_in[10];
    const float* gc2_bias = (const float*)d_in[11];
    const float* sw       = (const float*)d_in[12];
    const int*   src      = (const int*)d_in[13];
    const int*   dst      = (const int*)d_in[14];

    // ---- workspace layout (bytes) ----
    char* base = (char*)d_ws;
    unsigned short* h0b   = (unsigned short*)base;                    // NH bf16
    unsigned short* h1b   = h0b + NH;                                 // NH bf16
    unsigned short* agg2b = h0b;      // alias: h0 dead after gather1
    unsigned short* f0b   = h1b + NH;                                 // 40000*512
    unsigned short* f1b   = f0b + (size_t)40000 * 512;                // 30000*256
    unsigned short* f2b   = f1b + (size_t)30000 * 256;                // 30000*128
    unsigned short* w0b   = f2b + (size_t)30000 * 128;                // 256*512
    unsigned short* w1b   = w0b + 256 * 512;                          // 256*256
    unsigned short* w2b   = w1b + 256 * 256;                          // 256*128
    unsigned short* w2Tb  = w2b + 256 * 128;                          // 256*256
    float* nout = (float*)(w2Tb + 256 * 256 + 64);
    float* nin  = nout + NNODES;
    int* deg_out = (int*)(nin + NNODES);
    int* deg_in  = deg_out + NNODES;
    int* cursor  = deg_in + NNODES;
    int* row_off = cursor + NNODES;       // NNODES+1
    int* bsums   = row_off + NNODES + 1;  // 512
    int* csr_src = bsums + 512;           // NEDGES
    float* out   = (float*)d_out;

    // ---- graph preprocessing ----
    zero_i32_k<<<(3 * NNODES + 255) / 256, 256, 0, stream>>>(deg_out, 3 * NNODES);
    count_deg_k<<<(NEDGES + 255) / 256, 256, 0, stream>>>(src, dst, deg_out, deg_in);
    finalize_norm_k<<<(NNODES + 255) / 256, 256, 0, stream>>>(deg_out, deg_in, nout, nin,
                                                              sw, out + NH);
    scan_a_k<<<NSBLK, SCAN_B, 0, stream>>>(deg_in, row_off, bsums);
    scan_b_k<<<1, 512, 0, stream>>>(bsums);
    scan_c_k<<<NSBLK, SCAN_B, 0, stream>>>(row_off, bsums);
    fill_csr_k<<<(NEDGES + 255) / 256, 256, 0, stream>>>(src, dst, row_off, cursor, csr_src);

    // ---- fp32 -> bf16 conversions ----
    cvt_bf16_k<<<(40000 * 512 / 4 + 255) / 256, 256, 0, stream>>>(feat0, f0b, 40000 * 512 / 4);
    cvt_bf16_k<<<(30000 * 256 / 4 + 255) / 256, 256, 0, stream>>>(feat1, f1b, 30000 * 256 / 4);
    cvt_bf16_k<<<(30000 * 128 / 4 + 255) / 256, 256, 0, stream>>>(feat2, f2b, 30000 * 128 / 4);
    cvt_bf16_k<<<(256 * 512 / 4 + 255) / 256, 256, 0, stream>>>(fc_w0, w0b, 256 * 512 / 4);
    cvt_bf16_k<<<(256 * 256 / 4 + 255) / 256, 256, 0, stream>>>(fc_w1, w1b, 256 * 256 / 4);
    cvt_bf16_k<<<(256 * 128 / 4 + 255) / 256, 256, 0, stream>>>(fc_w2, w2b, 256 * 128 / 4);
    cvt_w2T_k<<<256, 256, 0, stream>>>(gc2_w, w2Tb);

    // ---- projections: h0 = (feat @ W.T + b) * norm_out  [bf16 out] ----
    mfma_gemm_k<0><<<dim3((40000 + 127) / 128, 2), 256, 0, stream>>>(
        f0b, w0b, fc_b0, nout, h0b, 40000, 512);
    mfma_gemm_k<0><<<dim3((30000 + 127) / 128, 2), 256, 0, stream>>>(
        f1b, w1b, fc_b1, nout + 40000, h0b + (size_t)40000 * HID, 30000, 256);
    mfma_gemm_k<0><<<dim3((30000 + 127) / 128, 2), 256, 0, stream>>>(
        f2b, w2b, fc_b2, nout + 70000, h0b + (size_t)70000 * HID, 30000, 128);

    // ---- layer 1: gather + fused epilogue -> h1 (bf16) ----
    gather_bf16_k<1><<<(NNODES + 3) / 4, 256, 0, stream>>>(h0b, row_off, csr_src,
                                                           nin, nout, gc1_bias, h1b);
    // ---- layer 2: gather -> agg2 (bf16), then MFMA GEMM -> d_out (fp32) ----
    gather_bf16_k<0><<<(NNODES + 3) / 4, 256, 0, stream>>>(h1b, row_off, csr_src,
                                                           nin, nout, nullptr, agg2b);
    mfma_gemm_k<1><<<dim3((100000 + 127) / 128, 2), 256, 0, stream>>>(
        agg2b, w2Tb, gc2_bias, nin, out, 100000, 256);
}

// Round 5
// 464.713 us; speedup vs baseline: 5.7476x; 1.0003x over previous
//
#include <hip/hip_runtime.h>
#include <cstdint>

#define HID 256
static constexpr int    NNODES = 100000;
static constexpr int    NEDGES = 300000;
static constexpr size_t NH     = (size_t)NNODES * HID;  // 25,600,000 elems
static constexpr int    SCAN_B = 256;
static constexpr int    NSBLK  = (NNODES + SCAN_B - 1) / SCAN_B;  // 391

typedef __attribute__((ext_vector_type(8))) short bf16x8;
typedef __attribute__((ext_vector_type(4))) float f32x4;

__device__ __forceinline__ unsigned short f2bf(float x) {   // RNE f32 -> bf16
    unsigned int u = __float_as_uint(x);
    u += 0x7fffu + ((u >> 16) & 1u);
    return (unsigned short)(u >> 16);
}
__device__ __forceinline__ unsigned int pack2(float a, float b) {
    return (unsigned int)f2bf(a) | ((unsigned int)f2bf(b) << 16);
}
__device__ __forceinline__ float bflo(unsigned int u) { return __uint_as_float(u << 16); }
__device__ __forceinline__ float bfhi(unsigned int u) { return __uint_as_float(u & 0xffff0000u); }

// ---------------------------------------------------------------- zero ints
__global__ void zero_i32_k(int* __restrict__ p, int n) {
    int i = blockIdx.x * blockDim.x + threadIdx.x;
    if (i < n) p[i] = 0;
}

// ---------------------------------------------------------------- degrees
__global__ void count_deg_k(const int* __restrict__ src, const int* __restrict__ dst,
                            int* __restrict__ degout, int* __restrict__ degin) {
    int e = blockIdx.x * blockDim.x + threadIdx.x;
    if (e < NEDGES) {
        atomicAdd(degout + src[e], 1);
        atomicAdd(degin  + dst[e], 1);
    }
}

// ---------------------------------------------------------------- weights -> bf16 (one launch)
// blocks 0..127: fc_w0 (131072 el), 128..191: fc_w1 (65536), 192..223: fc_w2 (32768),
// 224..479: gc2_w transpose -> n-major [256][256]
__global__ void cvt_weights_k(const float* __restrict__ w0, const float* __restrict__ w1,
                              const float* __restrict__ w2, const float* __restrict__ wg,
                              unsigned short* __restrict__ o0, unsigned short* __restrict__ o1,
                              unsigned short* __restrict__ o2, unsigned short* __restrict__ ogT) {
    int b = blockIdx.x, t = threadIdx.x;
    const float* in; unsigned short* out; int i;
    if (b < 128)      { in = w0; out = o0; i = b * 256 + t; }
    else if (b < 192) { in = w1; out = o1; i = (b - 128) * 256 + t; }
    else if (b < 224) { in = w2; out = o2; i = (b - 192) * 256 + t; }
    else {
        int n = b - 224, k = t;
        ogT[n * 256 + k] = f2bf(wg[k * 256 + n]);
        return;
    }
    float4 v = ((const float4*)in)[i];
    ushort4 w;
    w.x = f2bf(v.x); w.y = f2bf(v.y); w.z = f2bf(v.z); w.w = f2bf(v.w);
    ((ushort4*)out)[i] = w;
}

// ---------------------------------------------------------------- scan A (+ norms fused)
__global__ void scan_a_k(const int* __restrict__ degin, const int* __restrict__ degout,
                         int* __restrict__ row_off, int* __restrict__ bsums,
                         float* __restrict__ nout, float* __restrict__ nin,
                         const float* __restrict__ sw, float* __restrict__ tail) {
    __shared__ int sm[SCAN_B];
    int t = threadIdx.x;
    int g = blockIdx.x * SCAN_B + t;
    int v = (g < NNODES) ? degin[g] : 0;
    sm[t] = v;
    if (g < NNODES) {
        nout[g] = rsqrtf(fmaxf((float)degout[g], 1.0f));
        nin[g]  = rsqrtf(fmaxf((float)v, 1.0f));
    }
    if (g < 5) tail[g] = sw[g];   // semantic_weight passthrough
    __syncthreads();
#pragma unroll
    for (int off = 1; off < SCAN_B; off <<= 1) {
        int x = (t >= off) ? sm[t - off] : 0;
        __syncthreads();
        sm[t] += x;
        __syncthreads();
    }
    if (g < NNODES) row_off[g] = sm[t] - v;
    if (t == SCAN_B - 1) bsums[blockIdx.x] = sm[t];
}

__global__ void scan_b_k(int* __restrict__ bsums) {
    __shared__ int sm[512];
    int t = threadIdx.x;
    int v = (t < NSBLK) ? bsums[t] : 0;
    sm[t] = v;
    __syncthreads();
#pragma unroll
    for (int off = 1; off < 512; off <<= 1) {
        int x = (t >= off) ? sm[t - off] : 0;
        __syncthreads();
        sm[t] += x;
        __syncthreads();
    }
    if (t < NSBLK) bsums[t] = sm[t] - v;
}

__global__ void scan_c_k(int* __restrict__ row_off, const int* __restrict__ bsums) {
    int g = blockIdx.x * SCAN_B + threadIdx.x;
    if (g < NNODES) row_off[g] += bsums[blockIdx.x];
    if (g == 0) row_off[NNODES] = NEDGES;
}

// ---------------------------------------------------------------- CSR fill
__global__ void fill_csr_k(const int* __restrict__ src, const int* __restrict__ dst,
                           const int* __restrict__ row_off, int* __restrict__ cursor,
                           int* __restrict__ csr_src) {
    int e = blockIdx.x * blockDim.x + threadIdx.x;
    if (e < NEDGES) {
        int d = dst[e];
        int pos = row_off[d] + atomicAdd(cursor + d, 1);
        csr_src[pos] = src[e];
    }
}

// ---------------------------------------------------------------- gather layer 1 (bf16 h)
// out = relu( (sum in-edges h0[src]) * nin + bias ) * nout
__global__ __launch_bounds__(256) void gather_bf16_k(
    const unsigned short* __restrict__ h, const int* __restrict__ row_off,
    const int* __restrict__ csr_src, const float* __restrict__ nin,
    const float* __restrict__ nout, const float* __restrict__ bias,
    unsigned short* __restrict__ out)
{
    int node = blockIdx.x * 4 + (threadIdx.x >> 6);
    if (node >= NNODES) return;
    int lane = threadIdx.x & 63;
    int beg = row_off[node], end = row_off[node + 1];
    float a0 = 0.f, a1 = 0.f, a2 = 0.f, a3 = 0.f;
    for (int e = beg; e < end; ++e) {
        int s = csr_src[e];
        uint2 v = *(const uint2*)(h + (size_t)s * HID + lane * 4);
        a0 += bflo(v.x); a1 += bfhi(v.x);
        a2 += bflo(v.y); a3 += bfhi(v.y);
    }
    float ni = nin[node], no = nout[node];
    float4 bb = *(const float4*)(bias + lane * 4);
    a0 = fmaxf(fmaf(a0, ni, bb.x), 0.f) * no;
    a1 = fmaxf(fmaf(a1, ni, bb.y), 0.f) * no;
    a2 = fmaxf(fmaf(a2, ni, bb.z), 0.f) * no;
    a3 = fmaxf(fmaf(a3, ni, bb.w), 0.f) * no;
    ushort4 o;
    o.x = f2bf(a0); o.y = f2bf(a1); o.z = f2bf(a2); o.w = f2bf(a3);
    *(ushort4*)(out + (size_t)node * HID + lane * 4) = o;
}

// ---------------------------------------------------------------- projection MFMA GEMM
// One dispatch for all 3 segments. Tile m=64 x n=256, 4 waves (64x64 each),
// BK=32. A is fp32 (converted to bf16 in-register during staging). C bf16,
// val = (acc + bias[n]) * nout[m].
// LDS swizzle: 16B chunk c of row r at slot c ^ ((r>>1)&3)  (2-way free).
__global__ __launch_bounds__(256, 3) void proj_mfma_k(
    const float* __restrict__ f0, const float* __restrict__ f1, const float* __restrict__ f2,
    const unsigned short* __restrict__ w0, const unsigned short* __restrict__ w1,
    const unsigned short* __restrict__ w2,
    const float* __restrict__ b0, const float* __restrict__ b1, const float* __restrict__ b2,
    const float* __restrict__ nout, unsigned short* __restrict__ h0)
{
    __shared__ unsigned short As[64 * 32];    // 4 KB
    __shared__ unsigned short Bs[256 * 32];   // 16 KB

    int bx = blockIdx.x;
    const float* A; const unsigned short* B; const float* bias; const float* rs;
    unsigned short* C; int M, K;
    if (bx < 625)       { A = f0; B = w0; bias = b0; rs = nout;          C = h0;                          M = 40000; K = 512; }
    else if (bx < 1094) { bx -= 625;  A = f1; B = w1; bias = b1; rs = nout + 40000; C = h0 + (size_t)40000 * HID; M = 30000; K = 256; }
    else                { bx -= 1094; A = f2; B = w2; bias = b2; rs = nout + 70000; C = h0 + (size_t)70000 * HID; M = 30000; K = 128; }
    const int m0 = bx * 64;

    const int tid  = threadIdx.x;
    const int wn   = tid >> 6;        // 0..3 (n quarter)
    const int lane = tid & 63;
    const int half = lane >> 4;
    const int l15  = lane & 15;

    f32x4 acc[4][4];
#pragma unroll
    for (int i = 0; i < 4; ++i)
#pragma unroll
        for (int j = 0; j < 4; ++j)
#pragma unroll
            for (int r = 0; r < 4; ++r) acc[i][j][r] = 0.f;

    const int arow = tid >> 2, ac = tid & 3;          // A staging: 1 chunk/thread
    const int aslot = ac ^ ((arow >> 1) & 3);
    int agm = m0 + arow; if (agm > M - 1) agm = M - 1;

    for (int k0 = 0; k0 < K; k0 += 32) {
        // ---- stage A (64 rows x 4 chunks), fp32 -> bf16 in-register ----
        {
            const float* p = A + (size_t)agm * K + k0 + ac * 8;
            float4 v0 = *(const float4*)p;
            float4 v1 = *(const float4*)(p + 4);
            uint4 u;
            u.x = pack2(v0.x, v0.y); u.y = pack2(v0.z, v0.w);
            u.z = pack2(v1.x, v1.y); u.w = pack2(v1.z, v1.w);
            *(uint4*)&As[(arow * 4 + aslot) * 8] = u;
        }
        // ---- stage B (256 n-rows x 4 chunks), 4 chunks/thread ----
#pragma unroll
        for (int t = 0; t < 4; ++t) {
            int q = tid + t * 256;
            int row = q >> 2, c = q & 3;
            int slot = c ^ ((row >> 1) & 3);
            uint4 v = *(const uint4*)(B + (size_t)row * K + k0 + c * 8);
            *(uint4*)&Bs[(row * 4 + slot) * 8] = v;
        }
        __syncthreads();

        bf16x8 af[4], bfr[4];
#pragma unroll
        for (int i = 0; i < 4; ++i) {
            int m = i * 16 + l15;
            int ca = half ^ ((m >> 1) & 3);
            af[i] = *(const bf16x8*)&As[(m * 4 + ca) * 8];
            int n = wn * 64 + i * 16 + l15;
            int cb = half ^ ((n >> 1) & 3);
            bfr[i] = *(const bf16x8*)&Bs[(n * 4 + cb) * 8];
        }
#pragma unroll
        for (int i = 0; i < 4; ++i)
#pragma unroll
            for (int j = 0; j < 4; ++j)
                acc[i][j] = __builtin_amdgcn_mfma_f32_16x16x32_bf16(
                    af[i], bfr[j], acc[i][j], 0, 0, 0);
        __syncthreads();
    }

    float bj[4];
#pragma unroll
    for (int j = 0; j < 4; ++j) bj[j] = bias[wn * 64 + j * 16 + l15];
#pragma unroll
    for (int i = 0; i < 4; ++i)
#pragma unroll
        for (int r = 0; r < 4; ++r) {
            int m = m0 + i * 16 + (lane >> 4) * 4 + r;
            if (m >= M) continue;
            float rsm = rs[m];
#pragma unroll
            for (int j = 0; j < 4; ++j) {
                int n = wn * 64 + j * 16 + l15;
                C[(size_t)m * HID + n] = f2bf((acc[i][j][r] + bj[j]) * rsm);
            }
        }
}

// ---------------------------------------------------------------- final: fused gather + MFMA GEMM
// out[m][n] = relu( (sum in-edges h1[src])[k] @ W[k][n] * nin[m] + bias[n] )
// Tile m=64 x n=256; A gathered once into LDS (8 BK-panels of 64x32, swizzled).
__global__ __launch_bounds__(256, 3) void final_mfma_k(
    const unsigned short* __restrict__ h1, const int* __restrict__ row_off,
    const int* __restrict__ csr_src, const unsigned short* __restrict__ wT,
    const float* __restrict__ bias, const float* __restrict__ nin,
    float* __restrict__ out)
{
    __shared__ unsigned short As[8 * 64 * 32];   // 32 KB: panel p = k in [32p,32p+32)
    __shared__ unsigned short Bs[256 * 32];      // 16 KB

    const int m0   = blockIdx.x * 64;
    const int tid  = threadIdx.x;
    const int wv   = tid >> 6;
    const int lane = tid & 63;
    const int half = lane >> 4;
    const int l15  = lane & 15;

    // ---- gather phase: wave wv handles rows wv*16 .. wv*16+15 ----
    {
        const int p   = lane >> 3;          // panel of this lane's 4 elems
        const int c   = (lane >> 1) & 3;    // chunk within panel
        const int sub = (lane & 1) * 4;     // offset within 8-elem chunk
        for (int r8 = 0; r8 < 16; ++r8) {
            int r = wv * 16 + r8;
            int node = m0 + r; if (node > NNODES - 1) node = NNODES - 1;
            int beg = row_off[node], end = row_off[node + 1];
            float a0 = 0.f, a1 = 0.f, a2 = 0.f, a3 = 0.f;
            for (int e = beg; e < end; ++e) {
                int s = csr_src[e];
                uint2 v = *(const uint2*)(h1 + (size_t)s * HID + lane * 4);
                a0 += bflo(v.x); a1 += bfhi(v.x);
                a2 += bflo(v.y); a3 += bfhi(v.y);
            }
            int slot = c ^ ((r >> 1) & 3);
            ushort4 o;
            o.x = f2bf(a0); o.y = f2bf(a1); o.z = f2bf(a2); o.w = f2bf(a3);
            *(ushort4*)&As[p * 2048 + (r * 4 + slot) * 8 + sub] = o;
        }
    }
    __syncthreads();

    f32x4 acc[4][4];
#pragma unroll
    for (int i = 0; i < 4; ++i)
#pragma unroll
        for (int j = 0; j < 4; ++j)
#pragma unroll
            for (int r = 0; r < 4; ++r) acc[i][j][r] = 0.f;

    const int wn = wv;
    for (int step = 0; step < 8; ++step) {
        int k0 = step * 32;
        // ---- stage B (256 n-rows x 4 chunks), 4 chunks/thread ----
#pragma unroll
        for (int t = 0; t < 4; ++t) {
            int q = tid + t * 256;
            int row = q >> 2, c = q & 3;
            int slot = c ^ ((row >> 1) & 3);
            uint4 v = *(const uint4*)(wT + (size_t)row * 256 + k0 + c * 8);
            *(uint4*)&Bs[(row * 4 + slot) * 8] = v;
        }
        __syncthreads();

        bf16x8 af[4], bfr[4];
#pragma unroll
        for (int i = 0; i < 4; ++i) {
            int m = i * 16 + l15;
            int ca = half ^ ((m >> 1) & 3);
            af[i] = *(const bf16x8*)&As[step * 2048 + (m * 4 + ca) * 8];
            int n = wn * 64 + i * 16 + l15;
            int cb = half ^ ((n >> 1) & 3);
            bfr[i] = *(const bf16x8*)&Bs[(n * 4 + cb) * 8];
        }
#pragma unroll
        for (int i = 0; i < 4; ++i)
#pragma unroll
            for (int j = 0; j < 4; ++j)
                acc[i][j] = __builtin_amdgcn_mfma_f32_16x16x32_bf16(
                    af[i], bfr[j], acc[i][j], 0, 0, 0);
        __syncthreads();
    }

    float bj[4];
#pragma unroll
    for (int j = 0; j < 4; ++j) bj[j] = bias[wn * 64 + j * 16 + l15];
#pragma unroll
    for (int i = 0; i < 4; ++i)
#pragma unroll
        for (int r = 0; r < 4; ++r) {
            int m = m0 + i * 16 + (lane >> 4) * 4 + r;
            if (m >= NNODES) continue;
            float rsm = nin[m];
#pragma unroll
            for (int j = 0; j < 4; ++j) {
                int n = wn * 64 + j * 16 + l15;
                out[(size_t)m * HID + n] = fmaxf(fmaf(acc[i][j][r], rsm, bj[j]), 0.f);
            }
        }
}

// ---------------------------------------------------------------- launch
extern "C" void kernel_launch(void* const* d_in, const int* in_sizes, int n_in,
                              void* d_out, int out_size, void* d_ws, size_t ws_size,
                              hipStream_t stream)
{
    const float* feat0    = (const float*)d_in[0];
    const float* feat1    = (const float*)d_in[1];
    const float* feat2    = (const float*)d_in[2];
    const float* fc_w0    = (const float*)d_in[3];
    const float* fc_b0    = (const float*)d_in[4];
    const float* fc_w1    = (const float*)d_in[5];
    const float* fc_b1    = (const float*)d_in[6];
    const float* fc_w2    = (const float*)d_in[7];
    const float* fc_b2    = (const float*)d_in[8];
    const float* gc1_bias = (const float*)d_in[9];
    const float* gc2_w    = (const float*)d_in[10];
    const float* gc2_bias = (const float*)d_in[11];
    const float* sw       = (const float*)d_in[12];
    const int*   src      = (const int*)d_in[13];
    const int*   dst      = (const int*)d_in[14];

    // ---- workspace layout ----
    unsigned short* h0b  = (unsigned short*)d_ws;          // NH bf16
    unsigned short* h1b  = h0b + NH;                       // NH bf16
    unsigned short* w0b  = h1b + NH;                       // 256*512
    unsigned short* w1b  = w0b + 131072;                   // 256*256
    unsigned short* w2b  = w1b + 65536;                    // 256*128
    unsigned short* w2Tb = w2b + 32768;                    // 256*256 (n-major)
    float* nout = (float*)(w2Tb + 65536);
    float* nin  = nout + NNODES;
    int* deg_out = (int*)(nin + NNODES);
    int* deg_in  = deg_out + NNODES;
    int* cursor  = deg_in + NNODES;
    int* row_off = cursor + NNODES;       // NNODES+1
    int* bsums   = row_off + NNODES + 1;  // 512
    int* csr_src = bsums + 512;           // NEDGES
    float* out   = (float*)d_out;

    // ---- graph preprocessing + weight conversion ----
    zero_i32_k<<<(3 * NNODES + 255) / 256, 256, 0, stream>>>(deg_out, 3 * NNODES);
    cvt_weights_k<<<480, 256, 0, stream>>>(fc_w0, fc_w1, fc_w2, gc2_w,
                                           w0b, w1b, w2b, w2Tb);
    count_deg_k<<<(NEDGES + 255) / 256, 256, 0, stream>>>(src, dst, deg_out, deg_in);
    scan_a_k<<<NSBLK, SCAN_B, 0, stream>>>(deg_in, deg_out, row_off, bsums,
                                           nout, nin, sw, out + NH);
    scan_b_k<<<1, 512, 0, stream>>>(bsums);
    scan_c_k<<<NSBLK, SCAN_B, 0, stream>>>(row_off, bsums);
    fill_csr_k<<<(NEDGES + 255) / 256, 256, 0, stream>>>(src, dst, row_off, cursor, csr_src);

    // ---- projections (1 dispatch, fused fp32->bf16): h0 = (feat @ W.T + b)*nout ----
    proj_mfma_k<<<1563, 256, 0, stream>>>(feat0, feat1, feat2, w0b, w1b, w2b,
                                          fc_b0, fc_b1, fc_b2, nout, h0b);

    // ---- layer 1: gather + fused epilogue -> h1 (bf16) ----
    gather_bf16_k<<<(NNODES + 3) / 4, 256, 0, stream>>>(h0b, row_off, csr_src,
                                                        nin, nout, gc1_bias, h1b);

    // ---- layer 2: fused gather + GEMM -> d_out (fp32) ----
    final_mfma_k<<<(NNODES + 63) / 64, 256, 0, stream>>>(h1b, row_off, csr_src, w2Tb,
                                                         gc2_bias, nin, out);
}

// Round 6
// 404.882 us; speedup vs baseline: 6.5970x; 1.1478x over previous
//
#include <hip/hip_runtime.h>
#include <cstdint>

#define HID 256
static constexpr int    NNODES = 100000;
static constexpr int    NEDGES = 300000;
static constexpr size_t NH     = (size_t)NNODES * HID;  // 25,600,000 elems
static constexpr int    SCAN_B = 256;
static constexpr int    NSBLK  = (NNODES + SCAN_B - 1) / SCAN_B;  // 391

typedef __attribute__((ext_vector_type(8))) short bf16x8;
typedef __attribute__((ext_vector_type(4))) float f32x4;

__device__ __forceinline__ unsigned short f2bf(float x) {   // RNE f32 -> bf16
    unsigned int u = __float_as_uint(x);
    u += 0x7fffu + ((u >> 16) & 1u);
    return (unsigned short)(u >> 16);
}
__device__ __forceinline__ unsigned int pack2(float a, float b) {
    return (unsigned int)f2bf(a) | ((unsigned int)f2bf(b) << 16);
}
__device__ __forceinline__ float bflo(unsigned int u) { return __uint_as_float(u << 16); }
__device__ __forceinline__ float bfhi(unsigned int u) { return __uint_as_float(u & 0xffff0000u); }

// ---------------------------------------------------------------- zero ints
__global__ void zero_i32_k(int* __restrict__ p, int n) {
    int i = blockIdx.x * blockDim.x + threadIdx.x;
    if (i < n) p[i] = 0;
}

// ---------------------------------------------------------------- degrees
__global__ void count_deg_k(const int* __restrict__ src, const int* __restrict__ dst,
                            int* __restrict__ degout, int* __restrict__ degin) {
    int e = blockIdx.x * blockDim.x + threadIdx.x;
    if (e < NEDGES) {
        atomicAdd(degout + src[e], 1);
        atomicAdd(degin  + dst[e], 1);
    }
}

// ---------------------------------------------------------------- weights -> bf16 (one launch)
// blocks 0..127: fc_w0, 128..191: fc_w1, 192..223: fc_w2, 224..479: gc2_w transpose
__global__ void cvt_weights_k(const float* __restrict__ w0, const float* __restrict__ w1,
                              const float* __restrict__ w2, const float* __restrict__ wg,
                              unsigned short* __restrict__ o0, unsigned short* __restrict__ o1,
                              unsigned short* __restrict__ o2, unsigned short* __restrict__ ogT) {
    int b = blockIdx.x, t = threadIdx.x;
    const float* in; unsigned short* out; int i;
    if (b < 128)      { in = w0; out = o0; i = b * 256 + t; }
    else if (b < 192) { in = w1; out = o1; i = (b - 128) * 256 + t; }
    else if (b < 224) { in = w2; out = o2; i = (b - 192) * 256 + t; }
    else {
        int n = b - 224, k = t;
        ogT[n * 256 + k] = f2bf(wg[k * 256 + n]);
        return;
    }
    float4 v = ((const float4*)in)[i];
    ushort4 w;
    w.x = f2bf(v.x); w.y = f2bf(v.y); w.z = f2bf(v.z); w.w = f2bf(v.w);
    ((ushort4*)out)[i] = w;
}

// ---------------------------------------------------------------- scan A (+ norms fused)
__global__ void scan_a_k(const int* __restrict__ degin, const int* __restrict__ degout,
                         int* __restrict__ row_off, int* __restrict__ bsums,
                         float* __restrict__ nout, float* __restrict__ nin,
                         const float* __restrict__ sw, float* __restrict__ tail) {
    __shared__ int sm[SCAN_B];
    int t = threadIdx.x;
    int g = blockIdx.x * SCAN_B + t;
    int v = (g < NNODES) ? degin[g] : 0;
    sm[t] = v;
    if (g < NNODES) {
        nout[g] = rsqrtf(fmaxf((float)degout[g], 1.0f));
        nin[g]  = rsqrtf(fmaxf((float)v, 1.0f));
    }
    if (g < 5) tail[g] = sw[g];   // semantic_weight passthrough
    __syncthreads();
#pragma unroll
    for (int off = 1; off < SCAN_B; off <<= 1) {
        int x = (t >= off) ? sm[t - off] : 0;
        __syncthreads();
        sm[t] += x;
        __syncthreads();
    }
    if (g < NNODES) row_off[g] = sm[t] - v;
    if (t == SCAN_B - 1) bsums[blockIdx.x] = sm[t];
}

__global__ void scan_b_k(int* __restrict__ bsums) {
    __shared__ int sm[512];
    int t = threadIdx.x;
    int v = (t < NSBLK) ? bsums[t] : 0;
    sm[t] = v;
    __syncthreads();
#pragma unroll
    for (int off = 1; off < 512; off <<= 1) {
        int x = (t >= off) ? sm[t - off] : 0;
        __syncthreads();
        sm[t] += x;
        __syncthreads();
    }
    if (t < NSBLK) bsums[t] = sm[t] - v;
}

__global__ void scan_c_k(int* __restrict__ row_off, const int* __restrict__ bsums) {
    int g = blockIdx.x * SCAN_B + threadIdx.x;
    if (g < NNODES) row_off[g] += bsums[blockIdx.x];
    if (g == 0) row_off[NNODES] = NEDGES;
}

// ---------------------------------------------------------------- CSR fill
__global__ void fill_csr_k(const int* __restrict__ src, const int* __restrict__ dst,
                           const int* __restrict__ row_off, int* __restrict__ cursor,
                           int* __restrict__ csr_src) {
    int e = blockIdx.x * blockDim.x + threadIdx.x;
    if (e < NEDGES) {
        int d = dst[e];
        int pos = row_off[d] + atomicAdd(cursor + d, 1);
        csr_src[pos] = src[e];
    }
}

// ---------------------------------------------------------------- gather (wave per node)
// acc = sum_{in-edges} h[csr_src[e]]  -- indices prefetched coalesced, x4 unroll
// EPI=0: store bf16 raw sum.  EPI=1: store fp32 relu(acc*nin + bias).
template <int EPI>
__global__ __launch_bounds__(256) void gather_k(
    const unsigned short* __restrict__ h, const int* __restrict__ row_off,
    const int* __restrict__ csr_src, const float* __restrict__ nin,
    const float* __restrict__ bias, void* __restrict__ outv)
{
    int node = blockIdx.x * 4 + (threadIdx.x >> 6);
    if (node >= NNODES) return;
    int lane = threadIdx.x & 63;
    int beg = row_off[node], end = row_off[node + 1];
    float a0 = 0.f, a1 = 0.f, a2 = 0.f, a3 = 0.f;
    for (int base = beg; base < end; base += 64) {
        int cnt = end - base; if (cnt > 64) cnt = 64;
        int idx = csr_src[base + (lane < cnt ? lane : cnt - 1)];   // coalesced
        int j = 0;
        for (; j + 4 <= cnt; j += 4) {
            int s0 = __shfl(idx, j);
            int s1 = __shfl(idx, j + 1);
            int s2 = __shfl(idx, j + 2);
            int s3 = __shfl(idx, j + 3);
            uint2 v0 = *(const uint2*)(h + (size_t)s0 * HID + lane * 4);
            uint2 v1 = *(const uint2*)(h + (size_t)s1 * HID + lane * 4);
            uint2 v2 = *(const uint2*)(h + (size_t)s2 * HID + lane * 4);
            uint2 v3 = *(const uint2*)(h + (size_t)s3 * HID + lane * 4);
            a0 += bflo(v0.x) + bflo(v1.x) + bflo(v2.x) + bflo(v3.x);
            a1 += bfhi(v0.x) + bfhi(v1.x) + bfhi(v2.x) + bfhi(v3.x);
            a2 += bflo(v0.y) + bflo(v1.y) + bflo(v2.y) + bflo(v3.y);
            a3 += bfhi(v0.y) + bfhi(v1.y) + bfhi(v2.y) + bfhi(v3.y);
        }
        for (; j < cnt; ++j) {
            int s = __shfl(idx, j);
            uint2 v = *(const uint2*)(h + (size_t)s * HID + lane * 4);
            a0 += bflo(v.x); a1 += bfhi(v.x);
            a2 += bflo(v.y); a3 += bfhi(v.y);
        }
    }
    if (EPI) {
        float ni = nin[node];
        float4 bb = *(const float4*)(bias + lane * 4);
        float4 o;
        o.x = fmaxf(fmaf(a0, ni, bb.x), 0.f);
        o.y = fmaxf(fmaf(a1, ni, bb.y), 0.f);
        o.z = fmaxf(fmaf(a2, ni, bb.z), 0.f);
        o.w = fmaxf(fmaf(a3, ni, bb.w), 0.f);
        *(float4*)((float*)outv + (size_t)node * HID + lane * 4) = o;
    } else {
        ushort4 o;
        o.x = f2bf(a0); o.y = f2bf(a1); o.z = f2bf(a2); o.w = f2bf(a3);
        *(ushort4*)((unsigned short*)outv + (size_t)node * HID + lane * 4) = o;
    }
}

// ---------------------------------------------------------------- projection MFMA GEMM
// One dispatch, 3 segments. Tile m=64 x n=256, 4 waves, BK=32. A fp32 -> bf16
// in staging. C bf16 = (acc + bias[n]) * nout[m].
// LDS swizzle: 16B chunk c of row r at slot c ^ ((r>>1)&3)  (2-way free).
__global__ __launch_bounds__(256, 3) void proj_mfma_k(
    const float* __restrict__ f0, const float* __restrict__ f1, const float* __restrict__ f2,
    const unsigned short* __restrict__ w0, const unsigned short* __restrict__ w1,
    const unsigned short* __restrict__ w2,
    const float* __restrict__ b0, const float* __restrict__ b1, const float* __restrict__ b2,
    const float* __restrict__ nout, unsigned short* __restrict__ h0)
{
    __shared__ unsigned short As[64 * 32];    // 4 KB
    __shared__ unsigned short Bs[256 * 32];   // 16 KB

    int bx = blockIdx.x;
    const float* A; const unsigned short* B; const float* bias; const float* rs;
    unsigned short* C; int M, K;
    if (bx < 625)       { A = f0; B = w0; bias = b0; rs = nout;          C = h0;                          M = 40000; K = 512; }
    else if (bx < 1094) { bx -= 625;  A = f1; B = w1; bias = b1; rs = nout + 40000; C = h0 + (size_t)40000 * HID; M = 30000; K = 256; }
    else                { bx -= 1094; A = f2; B = w2; bias = b2; rs = nout + 70000; C = h0 + (size_t)70000 * HID; M = 30000; K = 128; }
    const int m0 = bx * 64;

    const int tid  = threadIdx.x;
    const int wn   = tid >> 6;
    const int lane = tid & 63;
    const int half = lane >> 4;
    const int l15  = lane & 15;

    f32x4 acc[4][4];
#pragma unroll
    for (int i = 0; i < 4; ++i)
#pragma unroll
        for (int j = 0; j < 4; ++j)
#pragma unroll
            for (int r = 0; r < 4; ++r) acc[i][j][r] = 0.f;

    const int arow = tid >> 2, ac = tid & 3;
    const int aslot = ac ^ ((arow >> 1) & 3);
    int agm = m0 + arow; if (agm > M - 1) agm = M - 1;

    for (int k0 = 0; k0 < K; k0 += 32) {
        {
            const float* p = A + (size_t)agm * K + k0 + ac * 8;
            float4 v0 = *(const float4*)p;
            float4 v1 = *(const float4*)(p + 4);
            uint4 u;
            u.x = pack2(v0.x, v0.y); u.y = pack2(v0.z, v0.w);
            u.z = pack2(v1.x, v1.y); u.w = pack2(v1.z, v1.w);
            *(uint4*)&As[(arow * 4 + aslot) * 8] = u;
        }
#pragma unroll
        for (int t = 0; t < 4; ++t) {
            int q = tid + t * 256;
            int row = q >> 2, c = q & 3;
            int slot = c ^ ((row >> 1) & 3);
            uint4 v = *(const uint4*)(B + (size_t)row * K + k0 + c * 8);
            *(uint4*)&Bs[(row * 4 + slot) * 8] = v;
        }
        __syncthreads();

        bf16x8 af[4], bfr[4];
#pragma unroll
        for (int i = 0; i < 4; ++i) {
            int m = i * 16 + l15;
            int ca = half ^ ((m >> 1) & 3);
            af[i] = *(const bf16x8*)&As[(m * 4 + ca) * 8];
            int n = wn * 64 + i * 16 + l15;
            int cb = half ^ ((n >> 1) & 3);
            bfr[i] = *(const bf16x8*)&Bs[(n * 4 + cb) * 8];
        }
#pragma unroll
        for (int i = 0; i < 4; ++i)
#pragma unroll
            for (int j = 0; j < 4; ++j)
                acc[i][j] = __builtin_amdgcn_mfma_f32_16x16x32_bf16(
                    af[i], bfr[j], acc[i][j], 0, 0, 0);
        __syncthreads();
    }

    float bj[4];
#pragma unroll
    for (int j = 0; j < 4; ++j) bj[j] = bias[wn * 64 + j * 16 + l15];
#pragma unroll
    for (int i = 0; i < 4; ++i)
#pragma unroll
        for (int r = 0; r < 4; ++r) {
            int m = m0 + i * 16 + (lane >> 4) * 4 + r;
            if (m >= M) continue;
            float rsm = rs[m];
#pragma unroll
            for (int j = 0; j < 4; ++j) {
                int n = wn * 64 + j * 16 + l15;
                C[(size_t)m * HID + n] = f2bf((acc[i][j][r] + bj[j]) * rsm);
            }
        }
}

// ---------------------------------------------------------------- mid GEMM
// h2pre[m][n] = sum_k epi(agg1[m][k]) * W[k][n],
//   epi(x) = relu(x * nin[m] + b1[k]) * nout[m]   (layer-1 epilogue, in staging)
// wT is n-major bf16 [256][256]. Output plain bf16.
__global__ __launch_bounds__(256, 3) void mid_mfma_k(
    const unsigned short* __restrict__ agg1, const unsigned short* __restrict__ wT,
    const float* __restrict__ b1, const float* __restrict__ nin,
    const float* __restrict__ nout, unsigned short* __restrict__ h2)
{
    __shared__ unsigned short As[64 * 32];    // 4 KB
    __shared__ unsigned short Bs[256 * 32];   // 16 KB

    const int m0   = blockIdx.x * 64;
    const int tid  = threadIdx.x;
    const int wn   = tid >> 6;
    const int lane = tid & 63;
    const int half = lane >> 4;
    const int l15  = lane & 15;

    f32x4 acc[4][4];
#pragma unroll
    for (int i = 0; i < 4; ++i)
#pragma unroll
        for (int j = 0; j < 4; ++j)
#pragma unroll
            for (int r = 0; r < 4; ++r) acc[i][j][r] = 0.f;

    const int arow = tid >> 2, ac = tid & 3;
    const int aslot = ac ^ ((arow >> 1) & 3);
    int agm = m0 + arow; if (agm > NNODES - 1) agm = NNODES - 1;
    const float ni = nin[agm], no = nout[agm];

    for (int k0 = 0; k0 < 256; k0 += 32) {
        {   // A stage: bf16 agg1 chunk -> epi -> bf16
            uint4 u = *(const uint4*)(agg1 + (size_t)agm * HID + k0 + ac * 8);
            float4 c0 = *(const float4*)(b1 + k0 + ac * 8);
            float4 c1 = *(const float4*)(b1 + k0 + ac * 8 + 4);
            float x0 = fmaxf(fmaf(bflo(u.x), ni, c0.x), 0.f) * no;
            float x1 = fmaxf(fmaf(bfhi(u.x), ni, c0.y), 0.f) * no;
            float x2 = fmaxf(fmaf(bflo(u.y), ni, c0.z), 0.f) * no;
            float x3 = fmaxf(fmaf(bfhi(u.y), ni, c0.w), 0.f) * no;
            float x4 = fmaxf(fmaf(bflo(u.z), ni, c1.x), 0.f) * no;
            float x5 = fmaxf(fmaf(bfhi(u.z), ni, c1.y), 0.f) * no;
            float x6 = fmaxf(fmaf(bflo(u.w), ni, c1.z), 0.f) * no;
            float x7 = fmaxf(fmaf(bfhi(u.w), ni, c1.w), 0.f) * no;
            uint4 o;
            o.x = pack2(x0, x1); o.y = pack2(x2, x3);
            o.z = pack2(x4, x5); o.w = pack2(x6, x7);
            *(uint4*)&As[(arow * 4 + aslot) * 8] = o;
        }
#pragma unroll
        for (int t = 0; t < 4; ++t) {
            int q = tid + t * 256;
            int row = q >> 2, c = q & 3;
            int slot = c ^ ((row >> 1) & 3);
            uint4 v = *(const uint4*)(wT + (size_t)row * 256 + k0 + c * 8);
            *(uint4*)&Bs[(row * 4 + slot) * 8] = v;
        }
        __syncthreads();

        bf16x8 af[4], bfr[4];
#pragma unroll
        for (int i = 0; i < 4; ++i) {
            int m = i * 16 + l15;
            int ca = half ^ ((m >> 1) & 3);
            af[i] = *(const bf16x8*)&As[(m * 4 + ca) * 8];
            int n = wn * 64 + i * 16 + l15;
            int cb = half ^ ((n >> 1) & 3);
            bfr[i] = *(const bf16x8*)&Bs[(n * 4 + cb) * 8];
        }
#pragma unroll
        for (int i = 0; i < 4; ++i)
#pragma unroll
            for (int j = 0; j < 4; ++j)
                acc[i][j] = __builtin_amdgcn_mfma_f32_16x16x32_bf16(
                    af[i], bfr[j], acc[i][j], 0, 0, 0);
        __syncthreads();
    }

#pragma unroll
    for (int i = 0; i < 4; ++i)
#pragma unroll
        for (int r = 0; r < 4; ++r) {
            int m = m0 + i * 16 + (lane >> 4) * 4 + r;
            if (m >= NNODES) continue;
#pragma unroll
            for (int j = 0; j < 4; ++j) {
                int n = wn * 64 + j * 16 + l15;
                h2[(size_t)m * HID + n] = f2bf(acc[i][j][r]);
            }
        }
}

// ---------------------------------------------------------------- launch
extern "C" void kernel_launch(void* const* d_in, const int* in_sizes, int n_in,
                              void* d_out, int out_size, void* d_ws, size_t ws_size,
                              hipStream_t stream)
{
    const float* feat0    = (const float*)d_in[0];
    const float* feat1    = (const float*)d_in[1];
    const float* feat2    = (const float*)d_in[2];
    const float* fc_w0    = (const float*)d_in[3];
    const float* fc_b0    = (const float*)d_in[4];
    const float* fc_w1    = (const float*)d_in[5];
    const float* fc_b1    = (const float*)d_in[6];
    const float* fc_w2    = (const float*)d_in[7];
    const float* fc_b2    = (const float*)d_in[8];
    const float* gc1_bias = (const float*)d_in[9];
    const float* gc2_w    = (const float*)d_in[10];
    const float* gc2_bias = (const float*)d_in[11];
    const float* sw       = (const float*)d_in[12];
    const int*   src      = (const int*)d_in[13];
    const int*   dst      = (const int*)d_in[14];

    // ---- workspace layout ----
    unsigned short* h0b  = (unsigned short*)d_ws;          // NH bf16 (later h2pre)
    unsigned short* agg1 = h0b + NH;                       // NH bf16
    unsigned short* h2b  = h0b;    // alias: h0 dead after gather1
    unsigned short* w0b  = agg1 + NH;                      // 256*512
    unsigned short* w1b  = w0b + 131072;                   // 256*256
    unsigned short* w2b  = w1b + 65536;                    // 256*128
    unsigned short* w2Tb = w2b + 32768;                    // 256*256 (n-major)
    float* nout = (float*)(w2Tb + 65536);
    float* nin  = nout + NNODES;
    int* deg_out = (int*)(nin + NNODES);
    int* deg_in  = deg_out + NNODES;
    int* cursor  = deg_in + NNODES;
    int* row_off = cursor + NNODES;       // NNODES+1
    int* bsums   = row_off + NNODES + 1;  // 512
    int* csr_src = bsums + 512;           // NEDGES
    float* out   = (float*)d_out;

    // ---- graph preprocessing + weight conversion ----
    zero_i32_k<<<(3 * NNODES + 255) / 256, 256, 0, stream>>>(deg_out, 3 * NNODES);
    cvt_weights_k<<<480, 256, 0, stream>>>(fc_w0, fc_w1, fc_w2, gc2_w,
                                           w0b, w1b, w2b, w2Tb);
    count_deg_k<<<(NEDGES + 255) / 256, 256, 0, stream>>>(src, dst, deg_out, deg_in);
    scan_a_k<<<NSBLK, SCAN_B, 0, stream>>>(deg_in, deg_out, row_off, bsums,
                                           nout, nin, sw, out + NH);
    scan_b_k<<<1, 512, 0, stream>>>(bsums);
    scan_c_k<<<NSBLK, SCAN_B, 0, stream>>>(row_off, bsums);
    fill_csr_k<<<(NEDGES + 255) / 256, 256, 0, stream>>>(src, dst, row_off, cursor, csr_src);

    // ---- projections: h0 = (feat @ W.T + b)*nout  [bf16] ----
    proj_mfma_k<<<1563, 256, 0, stream>>>(feat0, feat1, feat2, w0b, w1b, w2b,
                                          fc_b0, fc_b1, fc_b2, nout, h0b);

    // ---- layer 1 aggregate (raw sum): agg1 = A h0 ----
    gather_k<0><<<(NNODES + 3) / 4, 256, 0, stream>>>(h0b, row_off, csr_src,
                                                      nullptr, nullptr, agg1);

    // ---- h2pre = relu(agg1*nin + b1)*nout @ W   (epilogue fused into A-staging) ----
    mid_mfma_k<<<(NNODES + 63) / 64, 256, 0, stream>>>(agg1, w2Tb, gc1_bias,
                                                       nin, nout, h2b);

    // ---- layer 2 aggregate + final epilogue -> d_out (fp32) ----
    gather_k<1><<<(NNODES + 3) / 4, 256, 0, stream>>>(h2b, row_off, csr_src,
                                                      nin, gc2_bias, out);
}